// Round 10
// baseline (73.367 us; speedup 1.0000x reference)
//
#include <hip/hip_runtime.h>
#include <hip/hip_fp16.h>

// ---------------------------------------------------------------------------
// DotProductAttention: O = softmax((Q K^T / sqrt(128)) * p_q * p_k^T) V
// B=16, S=2048, D=128, fp32 in/out.
// Fold scale*p_q*log2(e) into Q, p_k into K (exact), cast fp16, flash-attn
// with swapped-QK^T 32x32x16 MFMAs in log2-softmax domain, split-K x2.
// Round 10: 4 WAVES/SIMD via register diet. 1024-thread blocks (16 waves =
// 8 q-subtiles x 2 key-halves), Q fragments live in LDS (image layout, read
// per-iter) instead of 32 VGPRs; each wave handles 32 keys (s = 16 regs).
// Total regs ~110 <= 128 -> launch_bounds(1024,4) -> 16 waves/CU = 4/SIMD,
// giving the scheduler 4 independent streams to overlap MFMA/VALU/LDS.
// Conflict-free K/V/Q image layouts (r9). fp32 ks-merge in freed LDS; fp16
// kh partial means + merge2 (r8).
// ---------------------------------------------------------------------------

typedef _Float16 f16x8 __attribute__((ext_vector_type(8)));
typedef float f32x16 __attribute__((ext_vector_type(16)));
typedef unsigned int u32x4 __attribute__((ext_vector_type(4)));

#define S_LEN 2048
#define DD 128
#define TILE_BYTES 16384     // 64 keys x 128 d x 2B (one image tile)
#define NT 32                // kv tiles of 64 keys per batch
#define NTH 16               // tiles per key-half (split-K factor 2)
#define PART_ROWS 32768      // 16 batches * 2048 q-rows
#define PART_STRIDE 4194304  // PART_ROWS * 128 elems per kh slab
#define LDS_K 65536          // K dbuf base (Q image at 0)
#define LDS_V 98304          // V dbuf base
#define LDS_ML 131072        // (m,l) exchange

#define EXP2(x) __builtin_amdgcn_exp2f(x)   // raw v_exp_f32 (2^x)

__device__ __forceinline__ unsigned int pk2(float a, float b) {
  __half2 h = __float22half2_rn(make_float2(a, b));
  return __builtin_bit_cast(unsigned int, h);
}

__device__ __forceinline__ void st8(void* dst, const float v[8]) {
  u32x4 u;
  u[0] = pk2(v[0], v[1]);
  u[1] = pk2(v[2], v[3]);
  u[2] = pk2(v[4], v[5]);
  u[3] = pk2(v[6], v[7]);
  *(u32x4*)dst = u;
}

__device__ __forceinline__ void gld16(const void* g, void* l) {
  __builtin_amdgcn_global_load_lds(
      (const __attribute__((address_space(1))) unsigned int*)g,
      (__attribute__((address_space(3))) unsigned int*)l, 16, 0, 0);
}

// --------------------------- pre-pass: Q --------------------------------
// Q' = fp16(Q * (log2e/sqrt(128)) * p_q[row]); row-major [B*S][128]
__global__ __launch_bounds__(256) void prep_q_k(const float* __restrict__ Q,
                                                const float* __restrict__ pq,
                                                char* __restrict__ qh) {
  size_t i = ((size_t)blockIdx.x * 256 + threadIdx.x) * 8;
  const float g = pq[i >> 7] * 0.12751743343158394f;  // (1/sqrt(128))*log2(e)
  float4 a = *(const float4*)(Q + i);
  float4 b = *(const float4*)(Q + i + 4);
  float v[8] = {a.x * g, a.y * g, a.z * g, a.w * g,
                b.x * g, b.y * g, b.z * g, b.w * g};
  st8(qh + i * 2, v);
}

// --------------------------- pre-pass: K,V images ------------------------
// CONFLICT-FREE layouts (16B chunk index i within a 16 KB tile):
// K: i = (kc*2+h)*64 + ksub*32 + c  -> K[key=ksub*32+c][d=kc*16+h*8 ..+8]
// V: i = ((kc*2+h)*4 + d)*32 + c    -> V^T[dd=d*32+c][key=kc*16+h*8 ..+8]
__global__ __launch_bounds__(256) void prep_kv(
    const float* __restrict__ K, const float* __restrict__ V,
    const float* __restrict__ pk, char* __restrict__ kimg,
    char* __restrict__ vimg) {
  __shared__ float vt[64 * 132];
  const int t = threadIdx.x;
  const int bid = blockIdx.x;
  const int bq = bid & 15;
  const int kt = bid >> 4;
  const size_t rowbase = (size_t)bq * S_LEN + kt * 64;

  // stage V tile (fp32) into padded LDS for the transpose
#pragma unroll
  for (int cc = 0; cc < 8; ++cc) {
    const int f = cc * 256 + t;
    const int row = f >> 5;
    const int col = (f & 31) * 4;
    *(float4*)(vt + row * 132 + col) = *(const float4*)(V + (rowbase + row) * DD + col);
  }

  // K image: pure global->global, fold p_k
  char* kdst = kimg + (size_t)(bq * NT + kt) * TILE_BYTES;
#pragma unroll
  for (int cc = 0; cc < 4; ++cc) {
    const int i = cc * 256 + t;
    const int cI = i & 31;
    const int ksub = (i >> 5) & 1;
    const int hI = (i >> 6) & 1;
    const int kcI = i >> 7;
    const int key = ksub * 32 + cI;
    const int d0 = kcI * 16 + hI * 8;
    const float g = pk[rowbase + key];
    const float* src = K + (rowbase + key) * DD + d0;
    float4 a = *(const float4*)(src);
    float4 b = *(const float4*)(src + 4);
    float v[8] = {a.x * g, a.y * g, a.z * g, a.w * g,
                  b.x * g, b.y * g, b.z * g, b.w * g};
    st8(kdst + i * 16, v);
  }

  __syncthreads();

  // V image from LDS transpose
  char* vdst = vimg + (size_t)(bq * NT + kt) * TILE_BYTES;
#pragma unroll
  for (int cc = 0; cc < 4; ++cc) {
    const int i = cc * 256 + t;
    const int cI = i & 31;
    const int dI = (i >> 5) & 3;
    const int hI = (i >> 7) & 1;
    const int kcI = i >> 8;
    const int key0 = kcI * 16 + hI * 8;
    const int dcol = dI * 32 + cI;
    float v[8];
#pragma unroll
    for (int e = 0; e < 8; ++e) v[e] = vt[(key0 + e) * 132 + dcol];
    st8(vdst + i * 16, v);
  }
}

// --------------------------- main attention ------------------------------
// 1024 threads = 16 waves: wid = qs*2 + ks; qs in [0,8) picks a 32-q subtile,
// ks in {0,1} the 32-key half of each 64-key tile. Q image staged to LDS once;
// per-iter fragments (Q,K,V) all read from LDS conflict-free. Block covers
// key range [kh*1024,(kh+1)*1024); emits fp16 partial means + (m,l) per row.
__global__ __launch_bounds__(1024, 4) void attn_main(const char* __restrict__ qh,
                                                     const char* __restrict__ kimg,
                                                     const char* __restrict__ vimg,
                                                     _Float16* __restrict__ part,
                                                     float2* __restrict__ mlws) {
  __shared__ float4 ldsraw[8448];  // 135168 B: Q 64K | K dbuf 32K | V dbuf 32K | ml 4K
  char* lds = (char*)ldsraw;
  const int tid = threadIdx.x;
  const int wid = tid >> 6;  // 0..15
  const int qs = wid >> 1;   // q subtile 0..7
  const int ks = wid & 1;    // key half 0..1
  const int lane = tid & 63;
  const int c = lane & 31;
  const int h = lane >> 5;
  const int bid = blockIdx.x;
  const int bq = 2 * (bid & 7) + ((bid >> 3) & 1);  // batch pinned to XCD
  const int qt = (bid >> 4) & 7;                    // q-tile (256 rows)
  const int kh = bid >> 7;                          // key-half 0..1
  const int q0 = qt * 256 + qs * 32;

  const char* kb = kimg + (size_t)(bq * NT + kh * NTH) * TILE_BYTES;
  const char* vb = vimg + (size_t)(bq * NT + kh * NTH) * TILE_BYTES;

  // ---- prologue: Q image into LDS (ks==0 waves) + stage K/V tile 0 ----
  if (ks == 0) {
    const char* qrow = qh + (size_t)(bq * S_LEN + q0 + c) * 256;
    char* qd = lds + qs * 8192 + h * 512 + c * 16;
#pragma unroll
    for (int kc = 0; kc < 8; ++kc)
      *(u32x4*)(qd + kc * 1024) = *(const u32x4*)(qrow + kc * 32 + h * 16);
  }
  gld16(kb + tid * 16, lds + LDS_K + tid * 16);
  gld16(vb + tid * 16, lds + LDS_V + tid * 16);

  f32x16 acc[4];
#pragma unroll
  for (int d = 0; d < 4; ++d) {
#pragma unroll
    for (int r = 0; r < 16; ++r) acc[d][r] = 0.f;
  }
  float m_run = -1.0e30f, l_run = 0.f;

  const char* qA = lds + qs * 8192 + h * 512 + c * 16;

  for (int t = 0; t < NTH; ++t) {
    __syncthreads();  // tile t staged (and Q image ready at t=0)
    const int cur = (t & 1) * TILE_BYTES;
    {
      const int nt2 = (t + 1 < NTH) ? (t + 1) : (NTH - 1);  // clamp: benign re-stage
      const int nxt = ((t + 1) & 1) * TILE_BYTES;
      gld16(kb + (size_t)nt2 * TILE_BYTES + tid * 16, lds + LDS_K + nxt + tid * 16);
      gld16(vb + (size_t)nt2 * TILE_BYTES + tid * 16, lds + LDS_V + nxt + tid * 16);
    }

    // S^T = K' Q'^T over this wave's 32-key half (8 MFMA, K and Q from LDS)
    const char* kA = lds + LDS_K + cur + h * 1024 + ks * 512 + c * 16;
    f32x16 s;
#pragma unroll
    for (int r = 0; r < 16; ++r) s[r] = 0.f;
    __builtin_amdgcn_s_setprio(1);
#pragma unroll
    for (int kc = 0; kc < 8; ++kc) {
      f16x8 kf = *(const f16x8*)(kA + kc * 2048);
      f16x8 qf = *(const f16x8*)(qA + kc * 1024);
      s = __builtin_amdgcn_mfma_f32_32x32x16_f16(kf, qf, s, 0, 0, 0);
    }
    __builtin_amdgcn_s_setprio(0);

    // lane-local online softmax (log2 domain; row q = c); tree reductions
    float m0 = fmaxf(fmaxf(s[0], s[1]), fmaxf(s[2], s[3]));
    float m1 = fmaxf(fmaxf(s[4], s[5]), fmaxf(s[6], s[7]));
    float m2 = fmaxf(fmaxf(s[8], s[9]), fmaxf(s[10], s[11]));
    float m3 = fmaxf(fmaxf(s[12], s[13]), fmaxf(s[14], s[15]));
    float cm = fmaxf(fmaxf(m0, m1), fmaxf(m2, m3));
    cm = fmaxf(cm, __shfl_xor(cm, 32));
    if (__any(cm > m_run + 11.0f)) {  // defer-max: rescale only on real growth
      const float mn = fmaxf(m_run, cm);
      const float al = EXP2(m_run - mn);
      m_run = mn;
      l_run *= al;
#pragma unroll
      for (int d = 0; d < 4; ++d) {
#pragma unroll
        for (int r = 0; r < 16; ++r) acc[d][r] *= al;
      }
    }
    float ps0 = 0.f, ps1 = 0.f;
#pragma unroll
    for (int r = 0; r < 8; ++r) {
      s[r] = EXP2(s[r] - m_run);         ps0 += s[r];
      s[r + 8] = EXP2(s[r + 8] - m_run); ps1 += s[r + 8];
    }
    l_run += ps0 + ps1;

    // PV: O^T += V^T P^T over the wave's two local 16-key chunks
    const char* vA = lds + LDS_V + cur + h * 2048 + c * 16;
#pragma unroll
    for (int kc = 0; kc < 2; ++kc) {
      const int A = kc * 8;
      const int Bb = A + 4;
      unsigned pA0 = pk2(s[A + 0], s[A + 1]);
      unsigned pA1 = pk2(s[A + 2], s[A + 3]);
      unsigned pB0 = pk2(s[Bb + 0], s[Bb + 1]);
      unsigned pB1 = pk2(s[Bb + 2], s[Bb + 3]);
      unsigned own0 = h ? pB0 : pA0;
      unsigned own1 = h ? pB1 : pA1;
      unsigned snd0 = h ? pA0 : pB0;
      unsigned snd1 = h ? pA1 : pB1;
      unsigned rcv0 = __shfl_xor(snd0, 32);
      unsigned rcv1 = __shfl_xor(snd1, 32);
      u32x4 pw;
      pw[0] = h ? rcv0 : own0;  // elems 0,1 (source half h=0)
      pw[1] = h ? rcv1 : own1;  // elems 2,3
      pw[2] = h ? own0 : rcv0;  // elems 4,5 (source half h=1)
      pw[3] = h ? own1 : rcv1;  // elems 6,7
      f16x8 pf = __builtin_bit_cast(f16x8, pw);
      const int kci = ks * 2 + kc;  // global 16-key chunk in tile
      __builtin_amdgcn_s_setprio(1);
#pragma unroll
      for (int d = 0; d < 4; ++d) {
        f16x8 vf = *(const f16x8*)(vA + kci * 4096 + d * 512);
        acc[d] = __builtin_amdgcn_mfma_f32_32x32x16_f16(vf, pf, acc[d], 0, 0, 0);
      }
      __builtin_amdgcn_s_setprio(0);
    }
  }

  // ---- epilogue: merge ks pair (fp32 T in freed LDS), store fp16 means ----
  l_run += __shfl_xor(l_run, 32);  // full half-range sum for row q=c

  __syncthreads();  // all waves done with Q/K/V regions
  float2* ml = (float2*)(lds + LDS_ML);
  if (h == 0) ml[wid * 32 + c] = make_float2(m_run, l_run);
  __syncthreads();
  const float2 po = ml[(wid ^ 1) * 32 + c];  // partner key-half (same qs)
  const float ms = fmaxf(m_run, po.x);
  const float lstar = l_run * EXP2(m_run - ms) + po.y * EXP2(po.x - ms);
  const float w = EXP2(m_run - ms) / lstar;  // -> T holds this kh's partial MEAN

  const int swz = (c & 7) << 4;
  char* T = lds;  // 256 q x 128 d fp32 (128KB, Q+K/V regions), swizzled rows
  if (ks == 0) {
#pragma unroll
    for (int d = 0; d < 4; ++d) {
#pragma unroll
      for (int rr = 0; rr < 4; ++rr) {
        const int dd = d * 32 + rr * 8 + h * 4;
        float4 v4;
        v4.x = acc[d][rr * 4 + 0] * w;
        v4.y = acc[d][rr * 4 + 1] * w;
        v4.z = acc[d][rr * 4 + 2] * w;
        v4.w = acc[d][rr * 4 + 3] * w;
        *(float4*)(T + (qs * 32 + c) * 512 + ((dd * 4) ^ swz)) = v4;
      }
    }
  }
  __syncthreads();
  if (ks == 1) {
#pragma unroll
    for (int d = 0; d < 4; ++d) {
#pragma unroll
      for (int rr = 0; rr < 4; ++rr) {
        const int dd = d * 32 + rr * 8 + h * 4;
        float4* p = (float4*)(T + (qs * 32 + c) * 512 + ((dd * 4) ^ swz));
        float4 tv = *p;
        tv.x += acc[d][rr * 4 + 0] * w;
        tv.y += acc[d][rr * 4 + 1] * w;
        tv.z += acc[d][rr * 4 + 2] * w;
        tv.w += acc[d][rr * 4 + 3] * w;
        *p = tv;
      }
    }
  }
  if (ks == 0 && h == 0)
    mlws[(size_t)kh * PART_ROWS + (size_t)bq * S_LEN + qt * 256 + qs * 32 + c] =
        make_float2(ms, lstar);
  __syncthreads();

  // coalesced fp16 copy T -> part[kh] (un-swizzle)
  _Float16* pdst = part + (size_t)kh * PART_STRIDE +
                   ((size_t)bq * S_LEN + qt * 256) * 128;
#pragma unroll
  for (int p = 0; p < 4; ++p) {
    const int idx = p * 1024 + tid;
    const int q = idx >> 4;           // 0..255
    const int d0 = (idx & 15) * 8;    // 8 floats per chunk
    const int swzT = (q & 7) << 4;
    float4 A = *(const float4*)(T + q * 512 + ((d0 * 4) ^ swzT));
    float4 Bv = *(const float4*)(T + q * 512 + (((d0 * 4) + 16) ^ swzT));
    float v[8] = {A.x, A.y, A.z, A.w, Bv.x, Bv.y, Bv.z, Bv.w};
    st8((void*)(pdst + q * 128 + d0), v);
  }
}

// --------------------------- split-K merge --------------------------------
// O[r][d] = (p0*l0*2^(m0-M) + p1*l1*2^(m1-M)) / (l0*2^(m0-M) + l1*2^(m1-M))
__global__ __launch_bounds__(256) void merge2(const _Float16* __restrict__ part,
                                              const float2* __restrict__ mlws,
                                              float* __restrict__ out) {
  const int t = blockIdx.x * 256 + threadIdx.x;
  const int d0 = (t & 15) * 8;
  const int r = t >> 4;  // global row = b*2048 + q
  const float2 a = mlws[r];
  const float2 b = mlws[PART_ROWS + r];
  const float M = fmaxf(a.x, b.x);
  const float wa = a.y * EXP2(a.x - M);
  const float wb = b.y * EXP2(b.x - M);
  const float inv = 1.f / (wa + wb);
  const float fa = wa * inv, fb = wb * inv;
  const f16x8 pa = *(const f16x8*)(part + (size_t)r * 128 + d0);
  const f16x8 pb = *(const f16x8*)(part + PART_STRIDE + (size_t)r * 128 + d0);
  float4 o0, o1;
  o0.x = fa * (float)pa[0] + fb * (float)pb[0];
  o0.y = fa * (float)pa[1] + fb * (float)pb[1];
  o0.z = fa * (float)pa[2] + fb * (float)pb[2];
  o0.w = fa * (float)pa[3] + fb * (float)pb[3];
  o1.x = fa * (float)pa[4] + fb * (float)pb[4];
  o1.y = fa * (float)pa[5] + fb * (float)pb[5];
  o1.z = fa * (float)pa[6] + fb * (float)pb[6];
  o1.w = fa * (float)pa[7] + fb * (float)pb[7];
  float* orow = out + (size_t)r * 128 + d0;
  *(float4*)orow = o0;
  *(float4*)(orow + 4) = o1;
}

// --------------------------- launcher ------------------------------------
extern "C" void kernel_launch(void* const* d_in, const int* in_sizes, int n_in,
                              void* d_out, int out_size, void* d_ws, size_t ws_size,
                              hipStream_t stream) {
  const float* Q = (const float*)d_in[0];
  const float* K = (const float*)d_in[1];
  const float* V = (const float*)d_in[2];
  const float* pq = (const float*)d_in[3];
  const float* pk = (const float*)d_in[4];
  float* out = (float*)d_out;
  char* ws = (char*)d_ws;
  char* qh = ws;                                   // 8 MB fp16 scaled Q
  char* kimg = ws + (8u << 20);                    // 8 MB K image (gated, linear-read)
  char* vimg = ws + (16u << 20);                   // 8 MB V image (transposed, linear-read)
  _Float16* part = (_Float16*)(ws + (24u << 20));  // 16 MB fp16 partial means (2 slabs)
  float2* mlws = (float2*)(ws + (42u << 20));      // 0.5 MB (m,l) per row per slab

  prep_q_k<<<2048, 256, 0, stream>>>(Q, pq, qh);
  prep_kv<<<512, 256, 0, stream>>>(K, V, pk, kimg, vimg);
  attn_main<<<256, 1024, 0, stream>>>(qh, kimg, vimg, part, mlws);
  merge2<<<2048, 256, 0, stream>>>(part, mlws, out);
}

// Round 11
// 67.907 us; speedup vs baseline: 1.0804x; 1.0804x over previous
//
#include <hip/hip_runtime.h>
#include <hip/hip_fp16.h>

// ---------------------------------------------------------------------------
// DotProductAttention: O = softmax((Q K^T / sqrt(128)) * p_q * p_k^T) V
// B=16, S=2048, D=128, fp32 in/out.
// Fold scale*p_q*log2(e) into Q (inline, in attn prologue), p_k into K (prep),
// fp16 operands, flash-attention with swapped-QK^T 32x32x16 MFMAs, log2-domain
// softmax. Round 11: consolidation — prep_q folded into attn, split-K and
// merge2 removed (direct fp32 out). Grid 256 (16 batches x 16 q-tiles of 128
// rows), 4-wave 256-thr blocks, 2 independent blocks/CU. Core = r8 inner loop
// (Q in regs, full 64-key tile per wave, conflict-free K/V image reads) with
// sm-split: exp slices interleaved into the PV chunk loop so each 4-MFMA
// cluster has independent VALU to overlap with.
// ---------------------------------------------------------------------------

typedef _Float16 f16x8 __attribute__((ext_vector_type(8)));
typedef float f32x16 __attribute__((ext_vector_type(16)));
typedef unsigned int u32x4 __attribute__((ext_vector_type(4)));

#define S_LEN 2048
#define DD 128
#define TILE_BYTES 16384   // 64 keys x 128 d x 2B (one image tile)
#define NT 32              // kv tiles of 64 keys per batch

#define EXP2(x) __builtin_amdgcn_exp2f(x)   // raw v_exp_f32 (2^x)

__device__ __forceinline__ unsigned int pk2(float a, float b) {
  __half2 h = __float22half2_rn(make_float2(a, b));
  return __builtin_bit_cast(unsigned int, h);
}

__device__ __forceinline__ void st8(void* dst, const float v[8]) {
  u32x4 u;
  u[0] = pk2(v[0], v[1]);
  u[1] = pk2(v[2], v[3]);
  u[2] = pk2(v[4], v[5]);
  u[3] = pk2(v[6], v[7]);
  *(u32x4*)dst = u;
}

__device__ __forceinline__ void gld16(const void* g, void* l) {
  __builtin_amdgcn_global_load_lds(
      (const __attribute__((address_space(1))) unsigned int*)g,
      (__attribute__((address_space(3))) unsigned int*)l, 16, 0, 0);
}

// --------------------------- pre-pass: K,V images ------------------------
// CONFLICT-FREE layouts (16B chunk index i within a 16 KB tile):
// K: i = (kc*2+h)*64 + ksub*32 + c  -> K[key=ksub*32+c][d=kc*16+h*8 ..+8]
// V: i = ((kc*2+h)*4 + d)*32 + c    -> V^T[dd=d*32+c][key=kc*16+h*8 ..+8]
__global__ __launch_bounds__(256) void prep_kv(
    const float* __restrict__ K, const float* __restrict__ V,
    const float* __restrict__ pk, char* __restrict__ kimg,
    char* __restrict__ vimg) {
  __shared__ float vt[64 * 132];
  const int t = threadIdx.x;
  const int bid = blockIdx.x;
  const int bq = bid & 15;
  const int kt = bid >> 4;
  const size_t rowbase = (size_t)bq * S_LEN + kt * 64;

  // stage V tile (fp32) into padded LDS for the transpose
#pragma unroll
  for (int cc = 0; cc < 8; ++cc) {
    const int f = cc * 256 + t;
    const int row = f >> 5;
    const int col = (f & 31) * 4;
    *(float4*)(vt + row * 132 + col) = *(const float4*)(V + (rowbase + row) * DD + col);
  }

  // K image: pure global->global, fold p_k
  char* kdst = kimg + (size_t)(bq * NT + kt) * TILE_BYTES;
#pragma unroll
  for (int cc = 0; cc < 4; ++cc) {
    const int i = cc * 256 + t;
    const int cI = i & 31;
    const int ksub = (i >> 5) & 1;
    const int hI = (i >> 6) & 1;
    const int kcI = i >> 7;
    const int key = ksub * 32 + cI;
    const int d0 = kcI * 16 + hI * 8;
    const float g = pk[rowbase + key];
    const float* src = K + (rowbase + key) * DD + d0;
    float4 a = *(const float4*)(src);
    float4 b = *(const float4*)(src + 4);
    float v[8] = {a.x * g, a.y * g, a.z * g, a.w * g,
                  b.x * g, b.y * g, b.z * g, b.w * g};
    st8(kdst + i * 16, v);
  }

  __syncthreads();

  // V image from LDS transpose
  char* vdst = vimg + (size_t)(bq * NT + kt) * TILE_BYTES;
#pragma unroll
  for (int cc = 0; cc < 4; ++cc) {
    const int i = cc * 256 + t;
    const int cI = i & 31;
    const int dI = (i >> 5) & 3;
    const int hI = (i >> 7) & 1;
    const int kcI = i >> 8;
    const int key0 = kcI * 16 + hI * 8;
    const int dcol = dI * 32 + cI;
    float v[8];
#pragma unroll
    for (int e = 0; e < 8; ++e) v[e] = vt[(key0 + e) * 132 + dcol];
    st8(vdst + i * 16, v);
  }
}

// --------------------------- main attention ------------------------------
// 256 threads = 4 waves; wave wid owns 32 q-rows (q0 = qt*128 + wid*32) and
// processes the FULL 64-key tile per iter (32 MFMAs). Q converted fp32->fp16
// inline (g = pq*log2e/sqrt(128) folded). Full key range, direct fp32 out.
__global__ __launch_bounds__(256, 2) void attn_main(const float* __restrict__ Q,
                                                    const float* __restrict__ pq,
                                                    const char* __restrict__ kimg,
                                                    const char* __restrict__ vimg,
                                                    float* __restrict__ out) {
  __shared__ float4 ldsraw[4096];  // 65536 B: 2 x (16KB K + 16KB V) dbuf; T aliases
  char* lds = (char*)ldsraw;
  const int tid = threadIdx.x;
  const int wid = tid >> 6;  // wave = q subtile 0..3
  const int lane = tid & 63;
  const int c = lane & 31;
  const int h = lane >> 5;
  const int bid = blockIdx.x;
  const int bq = 2 * (bid & 7) + ((bid >> 3) & 1);  // batch pinned to XCD
  const int qt = bid >> 4;                          // q-tile (128 rows) 0..15
  const int q0 = qt * 128 + wid * 32;

  const char* kb = kimg + (size_t)bq * (NT * TILE_BYTES);
  const char* vb = vimg + (size_t)bq * (NT * TILE_BYTES);

  // prologue: stage tile 0 + inline Q convert (row q0+c, fp32 -> fp16*g)
#pragma unroll
  for (int j = 0; j < 4; ++j) {
    gld16(kb + j * 4096 + tid * 16, lds + j * 4096 + tid * 16);
    gld16(vb + j * 4096 + tid * 16, lds + TILE_BYTES + j * 4096 + tid * 16);
  }

  const size_t qgrow = (size_t)bq * S_LEN + q0 + c;
  const float g = pq[qgrow] * 0.12751743343158394f;  // (1/sqrt(128))*log2(e)
  const float* qsrc = Q + qgrow * DD;
  f16x8 qf[8];
#pragma unroll
  for (int kc = 0; kc < 8; ++kc) {
    float4 a = *(const float4*)(qsrc + kc * 16 + h * 8);
    float4 b = *(const float4*)(qsrc + kc * 16 + h * 8 + 4);
    u32x4 u;
    u[0] = pk2(a.x * g, a.y * g);
    u[1] = pk2(a.z * g, a.w * g);
    u[2] = pk2(b.x * g, b.y * g);
    u[3] = pk2(b.z * g, b.w * g);
    qf[kc] = __builtin_bit_cast(f16x8, u);
  }

  f32x16 acc[4];
#pragma unroll
  for (int d = 0; d < 4; ++d) {
#pragma unroll
    for (int r = 0; r < 16; ++r) acc[d][r] = 0.f;
  }
  float m_run = -1.0e30f, l_run = 0.f;

  for (int kt = 0; kt < NT; ++kt) {
    __syncthreads();  // tile kt staged; other buffer free
    const int cur = (kt & 1) << 15;
    if (kt + 1 < NT) {
      const int nxt = ((kt + 1) & 1) << 15;
      const char* kn = kb + (size_t)(kt + 1) * TILE_BYTES;
      const char* vn = vb + (size_t)(kt + 1) * TILE_BYTES;
#pragma unroll
      for (int j = 0; j < 4; ++j) {
        gld16(kn + j * 4096 + tid * 16, lds + nxt + j * 4096 + tid * 16);
        gld16(vn + j * 4096 + tid * 16, lds + nxt + TILE_BYTES + j * 4096 + tid * 16);
      }
    }

    // S^T = K' Q'^T over the FULL 64-key tile (conflict-free image reads)
    const char* kA = lds + cur + h * 1024 + c * 16;
    f32x16 s0, s1;
#pragma unroll
    for (int r = 0; r < 16; ++r) { s0[r] = 0.f; s1[r] = 0.f; }
    __builtin_amdgcn_s_setprio(1);
#pragma unroll
    for (int kc = 0; kc < 8; ++kc) {
      f16x8 k0 = *(const f16x8*)(kA + kc * 2048);        // ksub 0
      f16x8 k1 = *(const f16x8*)(kA + kc * 2048 + 512);  // ksub 1
      s0 = __builtin_amdgcn_mfma_f32_32x32x16_f16(k0, qf[kc], s0, 0, 0, 0);
      s1 = __builtin_amdgcn_mfma_f32_32x32x16_f16(k1, qf[kc], s1, 0, 0, 0);
    }
    __builtin_amdgcn_s_setprio(0);

    // max reduction (log2 domain; row q = c spans lane's 32 keys + partner's)
    float m0 = fmaxf(fmaxf(s0[0], s0[1]), fmaxf(s0[2], s0[3]));
    float m1 = fmaxf(fmaxf(s0[4], s0[5]), fmaxf(s0[6], s0[7]));
    float m2 = fmaxf(fmaxf(s0[8], s0[9]), fmaxf(s0[10], s0[11]));
    float m3 = fmaxf(fmaxf(s0[12], s0[13]), fmaxf(s0[14], s0[15]));
    float m4 = fmaxf(fmaxf(s1[0], s1[1]), fmaxf(s1[2], s1[3]));
    float m5 = fmaxf(fmaxf(s1[4], s1[5]), fmaxf(s1[6], s1[7]));
    float m6 = fmaxf(fmaxf(s1[8], s1[9]), fmaxf(s1[10], s1[11]));
    float m7 = fmaxf(fmaxf(s1[12], s1[13]), fmaxf(s1[14], s1[15]));
    m0 = fmaxf(m0, m1); m2 = fmaxf(m2, m3); m4 = fmaxf(m4, m5); m6 = fmaxf(m6, m7);
    float cm = fmaxf(fmaxf(m0, m2), fmaxf(m4, m6));
    cm = fmaxf(cm, __shfl_xor(cm, 32));
    if (__any(cm > m_run + 11.0f)) {  // defer-max: rescale only on real growth
      const float mn = fmaxf(m_run, cm);
      const float al = EXP2(m_run - mn);
      m_run = mn;
      l_run *= al;
#pragma unroll
      for (int d = 0; d < 4; ++d) {
#pragma unroll
        for (int r = 0; r < 16; ++r) acc[d][r] *= al;
      }
    }

    // sm-split PV: per 16-key chunk, exp slice (independent VALU) + pack +
    // 4-MFMA cluster — scheduler overlaps chunk k+1's VALU with chunk k's MFMAs
    const char* vA = lds + cur + TILE_BYTES + h * 2048 + c * 16;
    float ps = 0.f;
#pragma unroll
    for (int kc = 0; kc < 4; ++kc) {
      const f32x16 pn = (kc < 2) ? s0 : s1;   // folds at unroll
      const int A = (kc & 1) * 8;
      float e0 = EXP2(pn[A + 0] - m_run), e1 = EXP2(pn[A + 1] - m_run);
      float e2 = EXP2(pn[A + 2] - m_run), e3 = EXP2(pn[A + 3] - m_run);
      float e4 = EXP2(pn[A + 4] - m_run), e5 = EXP2(pn[A + 5] - m_run);
      float e6 = EXP2(pn[A + 6] - m_run), e7 = EXP2(pn[A + 7] - m_run);
      ps += ((e0 + e1) + (e2 + e3)) + ((e4 + e5) + (e6 + e7));
      unsigned pA0 = pk2(e0, e1);
      unsigned pA1 = pk2(e2, e3);
      unsigned pB0 = pk2(e4, e5);
      unsigned pB1 = pk2(e6, e7);
      unsigned own0 = h ? pB0 : pA0;
      unsigned own1 = h ? pB1 : pA1;
      unsigned snd0 = h ? pA0 : pB0;
      unsigned snd1 = h ? pA1 : pB1;
      unsigned rcv0 = __shfl_xor(snd0, 32);
      unsigned rcv1 = __shfl_xor(snd1, 32);
      u32x4 pw;
      pw[0] = h ? rcv0 : own0;  // elems 0,1 (source half h=0)
      pw[1] = h ? rcv1 : own1;  // elems 2,3
      pw[2] = h ? own0 : rcv0;  // elems 4,5 (source half h=1)
      pw[3] = h ? own1 : rcv1;  // elems 6,7
      f16x8 pf = __builtin_bit_cast(f16x8, pw);
      __builtin_amdgcn_s_setprio(1);
#pragma unroll
      for (int d = 0; d < 4; ++d) {
        f16x8 vf = *(const f16x8*)(vA + kc * 4096 + d * 512);
        acc[d] = __builtin_amdgcn_mfma_f32_32x32x16_f16(vf, pf, acc[d], 0, 0, 0);
      }
      __builtin_amdgcn_s_setprio(0);
    }
    l_run += ps;
  }

  // ---- epilogue: normalize, transpose O^T -> O via LDS, fp32 store ----
  l_run += __shfl_xor(l_run, 32);  // full 64-key-tile sum for row q=c
  const float w = 1.0f / l_run;

  __syncthreads();  // all waves done with stage buffers
  const int swz = (c & 7) << 4;
  char* T = lds;  // 128 q x 128 d fp32 (64KB), swizzled rows
#pragma unroll
  for (int d = 0; d < 4; ++d) {
#pragma unroll
    for (int rr = 0; rr < 4; ++rr) {
      const int dd = d * 32 + rr * 8 + h * 4;
      float4 v4;
      v4.x = acc[d][rr * 4 + 0] * w;
      v4.y = acc[d][rr * 4 + 1] * w;
      v4.z = acc[d][rr * 4 + 2] * w;
      v4.w = acc[d][rr * 4 + 3] * w;
      *(float4*)(T + (wid * 32 + c) * 512 + ((dd * 4) ^ swz)) = v4;
    }
  }
  __syncthreads();

  float* obase = out + ((size_t)bq * S_LEN + qt * 128) * DD;
#pragma unroll
  for (int p = 0; p < 16; ++p) {
    const int idx = p * 256 + tid;
    const int q = idx >> 5;
    const int d0 = (idx & 31) * 4;
    float4 v4 = *(const float4*)(T + q * 512 + ((d0 * 4) ^ ((q & 7) << 4)));
    *(float4*)(obase + q * DD + d0) = v4;
  }
}

// --------------------------- launcher ------------------------------------
extern "C" void kernel_launch(void* const* d_in, const int* in_sizes, int n_in,
                              void* d_out, int out_size, void* d_ws, size_t ws_size,
                              hipStream_t stream) {
  const float* Q = (const float*)d_in[0];
  const float* K = (const float*)d_in[1];
  const float* V = (const float*)d_in[2];
  const float* pq = (const float*)d_in[3];
  const float* pk = (const float*)d_in[4];
  float* out = (float*)d_out;
  char* ws = (char*)d_ws;
  char* kimg = ws;                       // 8 MB K image (gated, linear-read)
  char* vimg = ws + (8u << 20);          // 8 MB V image (transposed, linear-read)

  prep_kv<<<512, 256, 0, stream>>>(K, V, pk, kimg, vimg);
  attn_main<<<256, 256, 0, stream>>>(Q, pq, kimg, vimg, out);
}